// Round 1
// baseline (428.733 us; speedup 1.0000x reference)
//
#include <hip/hip_runtime.h>
#include <hip/hip_bf16.h>
#include <stdint.h>
#include <stddef.h>

// Problem constants (reference: B=4, L=4096, D=64, fp32, multiplicative mask)
#define B_   4
#define L_   4096
#define D_   64
#define TK_  64                 // keys per tile
#define NKT  (L_/TK_)           // 64 k-tiles
#define TQ_  64                 // queries per block (4 waves x 16 rows)
#define NQB  (L_/TQ_)           // 64 q-blocks per batch
#define KROW 144                // padded row bytes: 64 bf16 = 128 B + 16 B pad

typedef __attribute__((ext_vector_type(8))) short bf16x8;
typedef __attribute__((ext_vector_type(4))) float f32x4;
typedef __attribute__((ext_vector_type(4))) unsigned short u16x4;

__device__ static inline unsigned short f2bf(float x) {
  union { __hip_bfloat16 h; unsigned short u; } cv;
  cv.h = __float2bfloat16(x);   // RNE
  return cv.u;
}

// ---------------------------------------------------------------------------
// Fully-fused single-pass flash attention, ZERO workspace.
// Rationale: the 402-405us plateau was dominated by ~159us 1-GiB
// fillBufferAligned dispatches (workspace poison) inside the timed window --
// our two kernels are each <158us per rocprof. This version does the
// fp32->bf16 K/V staging per-tile in-kernel (reg-stage + ds_write), so d_ws
// is never touched. Compute section is IDENTICAL to the verified kernel:
//   - K staged into permuted slots (slot=(kr&3)*16+(kr>>2), KROW=144) so
//     acc[t] col i16 = key 4*i16+t  => mask loads stay f32x4.
//   - V staged transposed [d][key] (identity key order), same layout prep
//     produced before.
// Layouts HW-verified (m89/m91/m120): A/B frag [idx=lane&15][k=quad*8+j];
// C/D col=lane&15, row=quad*4+reg.
// XCD swizzle: 2 XCDs per batch so per-XCD L2 holds one batch's fp32 K/V
// (2 MB < 4 MiB) -- the in-kernel re-read of K/V stays on-die.
// Mask stream (256 MB, read once) remains the roofline: ~43us at 6.3 TB/s.
// ---------------------------------------------------------------------------
__global__ __launch_bounds__(256) void attn_fused(
    const float* __restrict__ Q, const float* __restrict__ K,
    const float* __restrict__ V, const float* __restrict__ Mk,
    float* __restrict__ out) {
  __shared__ char Kbuf[2][TK_*KROW];
  __shared__ char Vbuf[2][TK_*KROW];
  __shared__ char Pbuf[4][16*KROW];      // per-wave P scratch

  // XCD-aware swizzle: blockIdx%8 ~ XCD; batch = xcd>>1 (2 XCDs per batch)
  const int idx = blockIdx.x;            // 0..255
  const int b   = (idx & 7) >> 1;        // 0..3
  const int qt  = ((idx >> 3) << 1) | (idx & 1);  // 0..63, bijective

  const int tid  = threadIdx.x;
  const int w    = tid >> 6;
  const int lane = tid & 63;
  const int i16  = lane & 15;
  const int quad = lane >> 4;
  const int q0   = qt*TQ_ + w*16;

  // staging thread mapping: thread owns 4 keys (kq*4..+4) x 4 d (dq*4..+4)
  const int dq = tid & 15;
  const int kq = tid >> 4;               // 0..15

  // Q A-frags with folded (1/sqrt(64))*log2(e): exp(s) = exp2(acc*mask)
  const float cs = 0.125f * 1.44269504088896f;
  bf16x8 aq[2];
  {
    const float* qp = Q + ((size_t)b*L_ + q0 + i16)*D_ + quad*8;
#pragma unroll
    for (int ks=0; ks<2; ++ks) {
      const f32x4* p = (const f32x4*)(qp + ks*32);
      f32x4 x0 = p[0], x1 = p[1];
      bf16x8 v;
      for (int j=0;j<4;++j) v[j]   = (short)f2bf(x0[j]*cs);
      for (int j=0;j<4;++j) v[4+j] = (short)f2bf(x1[j]*cs);
      aq[ks] = v;
    }
  }

  // mask base: row (q0+quad*4+r), col kt*64 + 4*i16 (+t within the f32x4)
  const float* mbase = Mk + ((size_t)b*L_ + q0 + quad*4)*(size_t)L_ + 4*i16;
  // K/V staging bases (per-thread)
  const float* kbase = K + ((size_t)b*L_ + kq*4)*D_ + dq*4;
  const float* vbase = V + ((size_t)b*L_ + kq*4)*D_ + dq*4;

  f32x4 O[4];
#pragma unroll
  for (int t=0;t<4;++t) O[t] = (f32x4){0.f,0.f,0.f,0.f};
  float l_acc[4] = {0.f,0.f,0.f,0.f};
  f32x4 cmv[4], nmv[4];
  f32x4 kreg[4], vreg[4];

  // prologue: issue tile-0 K/V/mask loads into regs
#pragma unroll
  for (int r=0;r<4;++r) {
    kreg[r] = *(const f32x4*)(kbase + (size_t)r*D_);
    vreg[r] = *(const f32x4*)(vbase + (size_t)r*D_);
    cmv[r]  = *(const f32x4*)(mbase + (size_t)r*L_);
  }
#pragma unroll
  for (int r=0;r<4;++r) nmv[r] = cmv[r];   // keep defined for last-iter copy

  for (int kt=0; kt<NKT; ++kt) {
    const int buf = kt & 1;

    // --- stage regs -> LDS (bf16): K permuted rows, V transposed ---
    {
      char* kb = Kbuf[buf]; char* vb = Vbuf[buf];
#pragma unroll
      for (int r=0;r<4;++r) {            // K row kr=kq*4+r -> slot r*16+kq
        u16x4 pk;
        for (int j=0;j<4;++j) pk[j] = f2bf(kreg[r][j]);
        *(u16x4*)(kb + (r*16+kq)*KROW + dq*8) = pk;
      }
#pragma unroll
      for (int e=0;e<4;++e) {            // V^T row d=dq*4+e, keys kq*4..+4
        u16x4 pv;
        for (int r=0;r<4;++r) pv[r] = f2bf(vreg[r][e]);
        *(u16x4*)(vb + (dq*4+e)*KROW + kq*8) = pv;
      }
    }
    __syncthreads();   // one barrier/tile: publishes buf, fences buf^1 reuse

    // --- issue next-tile global loads (after barrier: never force-drained;
    //     compiler inserts counted vmcnt at next iter's consume point) ---
    if (kt+1 < NKT) {
      const size_t roff = (size_t)(kt+1)*TK_*(size_t)D_;
      const size_t kc   = (size_t)(kt+1)*TK_;
#pragma unroll
      for (int r=0;r<4;++r) {
        kreg[r] = *(const f32x4*)(kbase + roff + (size_t)r*D_);
        vreg[r] = *(const f32x4*)(vbase + roff + (size_t)r*D_);
        nmv[r]  = *(const f32x4*)(mbase + (size_t)r*L_ + kc);
      }
    }

    // --- S = (Q*cs) K^T : 4 col-tiles x 2 k-steps ---
    f32x4 acc[4];
    const char* kb = Kbuf[buf];
#pragma unroll
    for (int t=0;t<4;++t) {
      acc[t] = (f32x4){0.f,0.f,0.f,0.f};
#pragma unroll
      for (int ks=0;ks<2;++ks) {
        bf16x8 bfr = *(const bf16x8*)(kb + (t*16+i16)*KROW + ks*64 + quad*16);
        acc[t] = __builtin_amdgcn_mfma_f32_16x16x32_bf16(aq[ks], bfr, acc[t], 0,0,0);
      }
    }

    // --- P = exp2(acc * mask); row sums. acc[t][r]: key 4*i16+t, row quad*4+r
    float p[16]; float rs[4] = {0.f,0.f,0.f,0.f};
#pragma unroll
    for (int t=0;t<4;++t)
#pragma unroll
      for (int r=0;r<4;++r) {
        float v = __builtin_amdgcn_exp2f(acc[t][r] * cmv[r][t]);
        p[t*4+r] = v; rs[r] += v;
      }
#pragma unroll
    for (int r=0;r<4;++r) {
      float s = rs[r];
      s += __shfl_xor(s, 1); s += __shfl_xor(s, 2);
      s += __shfl_xor(s, 4); s += __shfl_xor(s, 8);
      l_acc[r] += s;
    }

    // --- P -> own-wave LDS in A-layout; keys 4*i16+0..3 contiguous ---
    char* pb = Pbuf[w];
#pragma unroll
    for (int r=0;r<4;++r) {
      u16x4 pk;
      for (int t=0;t<4;++t) pk[t] = f2bf(p[t*4+r]);
      *(u16x4*)(pb + (quad*4+r)*KROW + i16*8) = pk;
    }

    // --- O += P V ---
    const char* vb = Vbuf[buf];
#pragma unroll
    for (int ks=0;ks<2;++ks) {
      bf16x8 af = *(const bf16x8*)(pb + i16*KROW + ks*64 + quad*16);
#pragma unroll
      for (int dt=0;dt<4;++dt) {
        bf16x8 vf = *(const bf16x8*)(vb + (dt*16+i16)*KROW + ks*64 + quad*16);
        O[dt] = __builtin_amdgcn_mfma_f32_16x16x32_bf16(af, vf, O[dt], 0,0,0);
      }
    }

#pragma unroll
    for (int r=0;r<4;++r) cmv[r] = nmv[r];
  }

  // epilogue: normalize by row sums, store fp32
  float inv[4];
#pragma unroll
  for (int r=0;r<4;++r) inv[r] = 1.0f / l_acc[r];
#pragma unroll
  for (int t=0;t<4;++t)
#pragma unroll
    for (int r=0;r<4;++r)
      out[((size_t)b*L_ + q0 + quad*4 + r)*D_ + t*16 + i16] = O[t][r]*inv[r];
}

extern "C" void kernel_launch(void* const* d_in, const int* in_sizes, int n_in,
                              void* d_out, int out_size, void* d_ws, size_t ws_size,
                              hipStream_t stream) {
  const float* Q  = (const float*)d_in[0];
  const float* K  = (const float*)d_in[1];
  const float* V  = (const float*)d_in[2];
  const float* Mk = (const float*)d_in[3];
  // d_k (d_in[4]) is compile-time 64
  (void)d_ws; (void)ws_size;   // workspace intentionally UNUSED

  attn_fused<<<B_*NQB, 256, 0, stream>>>(Q, K, V, Mk, (float*)d_out);
}

// Round 2
// 407.492 us; speedup vs baseline: 1.0521x; 1.0521x over previous
//
#include <hip/hip_runtime.h>
#include <hip/hip_bf16.h>
#include <stdint.h>
#include <stddef.h>

// Problem constants (reference: B=4, L=4096, D=64, fp32, multiplicative mask)
#define B_   4
#define L_   4096
#define D_   64
#define TK_  64                 // keys per tile
#define NKT  (L_/TK_)           // 64 k-tiles total
#define NKH  (NKT/2)            // 32 k-tiles per half (2-way k-split)
#define TQ_  64                 // queries per block (4 q-waves x 16 rows)
#define NQB  (L_/TQ_)           // 64 q-blocks per batch
#define KROW 144                // padded row bytes: 64 bf16 = 128 B + 16 B pad
#define TILE_BYTES (TK_*KROW)

typedef __attribute__((ext_vector_type(8))) short bf16x8;
typedef __attribute__((ext_vector_type(4))) float f32x4;
typedef __attribute__((ext_vector_type(4))) unsigned short u16x4;

__device__ static inline unsigned short f2bf(float x) {
  union { __hip_bfloat16 h; unsigned short u; } cv;
  cv.h = __float2bfloat16(x);   // RNE
  return cv.u;
}

// ---------------------------------------------------------------------------
// Fully-fused flash attention, zero workspace, 2-way K-SPLIT per block.
// Round-1 diagnosis: 4 waves/CU (1/SIMD, Occupancy 11.5%) made the kernel
// pure-latency-bound (162us vs ~45us mask-stream roofline; MfmaUtil 4%,
// VALUBusy 12%, HBM 11%). The q-decomposition caps waves at 4/CU, so this
// version splits the KEY dimension across two wave-groups:
//   waves 0-3 (half 0): k-tiles  0..31     waves 4-7 (half 1): k-tiles 32..63
// Softmax here is STATIC (exp2(s*mask), no running max) so the split is
// exactly linear: O = O0+O1, l = l0+l1 -- combined through LDS at the end.
// Compute section per half is IDENTICAL to the verified round-1 kernel:
//   - K staged permuted (slot=(kr&3)*16+(kr>>2), KROW=144) => mask f32x4.
//   - V staged transposed [d][key].
//   - Layouts HW-verified (m89/m91/m120): A/B frag [idx=lane&15][k=quad*8+j];
//     C/D col=lane&15, row=quad*4+reg.
// LDS: 2halves x dbuf x (K+V) = 73.7KB + 8x2.25KB Pbuf = 92KB -> 1 block/CU,
// 8 waves/CU = 2/SIMD (2x round-1).
// XCD swizzle: 2 XCDs per batch; per-XCD L2 holds one batch's fp32 K/V (2MB).
// ---------------------------------------------------------------------------
__global__ __launch_bounds__(512) void attn_fused(
    const float* __restrict__ Q, const float* __restrict__ K,
    const float* __restrict__ V, const float* __restrict__ Mk,
    float* __restrict__ out) {
  __shared__ char Kbuf[2][2][TILE_BYTES];   // [half][buf]
  __shared__ char Vbuf[2][2][TILE_BYTES];
  __shared__ char Pbuf[8][16*KROW];         // per-wave P scratch

  // XCD-aware swizzle: blockIdx%8 ~ XCD; batch = xcd>>1 (2 XCDs per batch)
  const int idx = blockIdx.x;               // 0..255
  const int b   = (idx & 7) >> 1;           // 0..3
  const int qt  = ((idx >> 3) << 1) | (idx & 1);  // 0..63, bijective

  const int tid  = threadIdx.x;
  const int w    = tid >> 6;                // 0..7
  const int qw   = w & 3;                   // q-wave within half
  const int half = w >> 2;                  // k-split half
  const int lane = tid & 63;
  const int i16  = lane & 15;
  const int quad = lane >> 4;
  const int q0   = qt*TQ_ + qw*16;

  // staging thread mapping within a half: 256 threads own 4 keys x 4 d each
  const int st = tid & 255;
  const int dq = st & 15;
  const int kq = st >> 4;                   // 0..15

  // Q A-frags with folded (1/sqrt(64))*log2(e): exp(s) = exp2(acc*mask)
  const float cs = 0.125f * 1.44269504088896f;
  bf16x8 aq[2];
  {
    const float* qp = Q + ((size_t)b*L_ + q0 + i16)*D_ + quad*8;
#pragma unroll
    for (int ks=0; ks<2; ++ks) {
      const f32x4* p = (const f32x4*)(qp + ks*32);
      f32x4 x0 = p[0], x1 = p[1];
      bf16x8 v;
      for (int j=0;j<4;++j) v[j]   = (short)f2bf(x0[j]*cs);
      for (int j=0;j<4;++j) v[4+j] = (short)f2bf(x1[j]*cs);
      aq[ks] = v;
    }
  }

  // mask base: row (q0+quad*4+r), col half*2048 + ktl*64 + 4*i16 (+t in f32x4)
  const float* mbase = Mk + ((size_t)b*L_ + q0 + quad*4)*(size_t)L_
                          + half*(NKH*TK_) + 4*i16;
  // K/V staging bases (per-thread, within this half's key range)
  const size_t krow0 = (size_t)b*L_ + (size_t)half*(NKH*TK_) + kq*4;
  const float* kbase = K + krow0*D_ + dq*4;
  const float* vbase = V + krow0*D_ + dq*4;

  f32x4 O[4];
#pragma unroll
  for (int t=0;t<4;++t) O[t] = (f32x4){0.f,0.f,0.f,0.f};
  float l_acc[4] = {0.f,0.f,0.f,0.f};
  f32x4 cmv[4], nmv[4];
  f32x4 kreg[4], vreg[4];

  // prologue: issue tile-0 K/V/mask loads into regs
#pragma unroll
  for (int r=0;r<4;++r) {
    kreg[r] = *(const f32x4*)(kbase + (size_t)r*D_);
    vreg[r] = *(const f32x4*)(vbase + (size_t)r*D_);
    cmv[r]  = *(const f32x4*)(mbase + (size_t)r*L_);
  }
#pragma unroll
  for (int r=0;r<4;++r) nmv[r] = cmv[r];   // keep defined for last-iter copy

  for (int kt=0; kt<NKH; ++kt) {
    const int buf = kt & 1;

    // --- stage regs -> LDS (bf16): K permuted rows, V transposed ---
    {
      char* kb = Kbuf[half][buf]; char* vb = Vbuf[half][buf];
#pragma unroll
      for (int r=0;r<4;++r) {            // K row kr=kq*4+r -> slot r*16+kq
        u16x4 pk;
        for (int j=0;j<4;++j) pk[j] = f2bf(kreg[r][j]);
        *(u16x4*)(kb + (r*16+kq)*KROW + dq*8) = pk;
      }
#pragma unroll
      for (int e=0;e<4;++e) {            // V^T row d=dq*4+e, keys kq*4..+4
        u16x4 pv;
        for (int r=0;r<4;++r) pv[r] = f2bf(vreg[r][e]);
        *(u16x4*)(vb + (dq*4+e)*KROW + kq*8) = pv;
      }
    }
    __syncthreads();   // one barrier/tile: publishes buf, fences buf^1 reuse

    // --- issue next-tile global loads (after barrier: counted-wait at
    //     next iter's staging consume, never force-drained here) ---
    if (kt+1 < NKH) {
      const size_t roff = (size_t)(kt+1)*TK_*(size_t)D_;
      const size_t kc   = (size_t)(kt+1)*TK_;
#pragma unroll
      for (int r=0;r<4;++r) {
        kreg[r] = *(const f32x4*)(kbase + roff + (size_t)r*D_);
        vreg[r] = *(const f32x4*)(vbase + roff + (size_t)r*D_);
        nmv[r]  = *(const f32x4*)(mbase + (size_t)r*L_ + kc);
      }
    }

    // --- S = (Q*cs) K^T : 4 col-tiles x 2 k-steps ---
    f32x4 acc[4];
    const char* kb = Kbuf[half][buf];
#pragma unroll
    for (int t=0;t<4;++t) {
      acc[t] = (f32x4){0.f,0.f,0.f,0.f};
#pragma unroll
      for (int ks=0;ks<2;++ks) {
        bf16x8 bfr = *(const bf16x8*)(kb + (t*16+i16)*KROW + ks*64 + quad*16);
        acc[t] = __builtin_amdgcn_mfma_f32_16x16x32_bf16(aq[ks], bfr, acc[t], 0,0,0);
      }
    }

    // --- P = exp2(acc * mask); row sums. acc[t][r]: key 4*i16+t, row quad*4+r
    float p[16]; float rs[4] = {0.f,0.f,0.f,0.f};
#pragma unroll
    for (int t=0;t<4;++t)
#pragma unroll
      for (int r=0;r<4;++r) {
        float v = __builtin_amdgcn_exp2f(acc[t][r] * cmv[r][t]);
        p[t*4+r] = v; rs[r] += v;
      }
#pragma unroll
    for (int r=0;r<4;++r) {
      float s = rs[r];
      s += __shfl_xor(s, 1); s += __shfl_xor(s, 2);
      s += __shfl_xor(s, 4); s += __shfl_xor(s, 8);
      l_acc[r] += s;
    }

    // --- P -> own-wave LDS in A-layout; keys 4*i16+0..3 contiguous ---
    char* pb = Pbuf[w];
#pragma unroll
    for (int r=0;r<4;++r) {
      u16x4 pk;
      for (int t=0;t<4;++t) pk[t] = f2bf(p[t*4+r]);
      *(u16x4*)(pb + (quad*4+r)*KROW + i16*8) = pk;
    }

    // --- O += P V ---
    const char* vb = Vbuf[half][buf];
#pragma unroll
    for (int ks=0;ks<2;++ks) {
      bf16x8 af = *(const bf16x8*)(pb + i16*KROW + ks*64 + quad*16);
#pragma unroll
      for (int dt=0;dt<4;++dt) {
        bf16x8 vf = *(const bf16x8*)(vb + (dt*16+i16)*KROW + ks*64 + quad*16);
        O[dt] = __builtin_amdgcn_mfma_f32_16x16x32_bf16(af, vf, O[dt], 0,0,0);
      }
    }

#pragma unroll
    for (int r=0;r<4;++r) cmv[r] = nmv[r];
  }

  // ---- k-split combine: O = O0+O1, l = l0+l1 (exact: static softmax) ----
  // Overlay scratch on Kbuf/Pbuf (all tile reads are done after this sync).
  float* Ol = (float*)&Kbuf[0][0][0];   // [4 qw][64 col][20]  (16 rows + pad)
  float* Ll = (float*)&Pbuf[0][0];      // [4 qw][16 rows]
  __syncthreads();
  if (half == 1) {
#pragma unroll
    for (int t=0;t<4;++t)
      *(f32x4*)&Ol[((size_t)qw*64 + t*16 + i16)*20 + quad*4] = O[t];
    if (i16 == 0) {
#pragma unroll
      for (int r=0;r<4;++r) Ll[qw*16 + quad*4 + r] = l_acc[r];
    }
  }
  __syncthreads();
  if (half == 0) {
#pragma unroll
    for (int t=0;t<4;++t) {
      f32x4 op = *(const f32x4*)&Ol[((size_t)qw*64 + t*16 + i16)*20 + quad*4];
      O[t] += op;
    }
    float inv[4];
#pragma unroll
    for (int r=0;r<4;++r) inv[r] = 1.0f / (l_acc[r] + Ll[qw*16 + quad*4 + r]);
#pragma unroll
    for (int t=0;t<4;++t)
#pragma unroll
      for (int r=0;r<4;++r)
        out[((size_t)b*L_ + q0 + quad*4 + r)*D_ + t*16 + i16] = O[t][r]*inv[r];
  }
}

extern "C" void kernel_launch(void* const* d_in, const int* in_sizes, int n_in,
                              void* d_out, int out_size, void* d_ws, size_t ws_size,
                              hipStream_t stream) {
  const float* Q  = (const float*)d_in[0];
  const float* K  = (const float*)d_in[1];
  const float* V  = (const float*)d_in[2];
  const float* Mk = (const float*)d_in[3];
  // d_k (d_in[4]) is compile-time 64
  (void)d_ws; (void)ws_size;   // workspace intentionally UNUSED

  attn_fused<<<B_*NQB, 512, 0, stream>>>(Q, K, V, Mk, (float*)d_out);
}

// Round 5
// 389.871 us; speedup vs baseline: 1.0997x; 1.0452x over previous
//
#include <hip/hip_runtime.h>
#include <hip/hip_bf16.h>
#include <stdint.h>
#include <stddef.h>

// Problem constants (reference: B=4, L=4096, D=64, fp32, multiplicative mask)
#define B_   4
#define L_   4096
#define D_   64
#define TK_  64                 // keys per tile
#define NKT  (L_/TK_)           // 64 k-tiles total
#define NKH  (NKT/2)            // 32 k-tiles per half (2-way k-split)
#define TQ_  64                 // queries per block (4 q-waves x 16 rows)
#define NQB  (L_/TQ_)           // 64 q-blocks per batch
#define KROW 144                // padded row bytes: 64 bf16 = 128 B + 16 B pad
#define TILE_BYTES (TK_*KROW)   // 9216 B = 9 x 1KB chunks

typedef __attribute__((ext_vector_type(8))) short bf16x8;
typedef __attribute__((ext_vector_type(4))) float f32x4;
typedef __attribute__((ext_vector_type(4))) unsigned short u16x4;

__device__ static inline unsigned short f2bf(float x) {
  union { __hip_bfloat16 h; unsigned short u; } cv;
  cv.h = __float2bfloat16(x);   // RNE
  return cv.u;
}

// ---------------------------------------------------------------------------
// Round-5: same theory as round 3/4 (remove in-loop staging VALU/LDS work via
// prep_kv; row sums onto the idle MFMA pipe), REDUCED RISK SURFACE: no
// global_load_lds (two consecutive container failures with that binary; this
// variant reverts staging to the round-2 harness-verified reg-copy schedule,
// now moving pre-converted bf16 instead of fp32+f2bf+transpose).
//   prep_kv: verified round-0.  8-wave k-split + 1 barrier/tile + combine
//   epilogue: verified round-2 (<161us).  New: bf16x8 chunk copy (5 loads +
//   5 ds_write_b128 per wave/tile, linear, conflict-free) and ones-MFMA row
//   sums accumulated in the C operand (l sums the same bf16 P used in PV).
// Layouts HW-verified (m89/m91/m120): A/B frag [idx=lane&15][k=quad*8+j];
// C/D col=lane&15, row=quad*4+reg. K permuted slot=(kr&3)*16+(kr>>2) so
// acc[t] col i16 = key 4*i16+t => mask loads stay f32x4.
// Mask stream (256 MB, read once) is the roofline: ~43us at 6.3 TB/s.
// ---------------------------------------------------------------------------

// Prep: K -> bf16 PERMUTED row tiles; V -> bf16 TRANSPOSED tiles [d][key].
__global__ __launch_bounds__(256) void prep_kv(const float* __restrict__ K,
                                               const float* __restrict__ V,
                                               char* __restrict__ kws,
                                               char* __restrict__ vws) {
  const int blk = blockIdx.x;        // b*NKT + kt
  const int kt  = blk & (NKT-1);
  const int b   = blk >> 6;
  const int t   = threadIdx.x;
  const int kr  = t >> 2;            // 0..63 key row in tile
  const int ds  = t & 3;             // 16-d segment
  const size_t row = (size_t)b*L_ + (size_t)kt*TK_ + kr;
  const f32x4* kp = (const f32x4*)(K + row*D_ + ds*16);
  const f32x4* vp = (const f32x4*)(V + row*D_ + ds*16);
  f32x4 kv[4], vv[4];
  for (int s=0;s<4;++s){ kv[s]=kp[s]; vv[s]=vp[s]; }

  bf16x8 lo, hi;
  for (int s=0;s<2;++s) for (int j=0;j<4;++j) lo[s*4+j] = (short)f2bf(kv[s  ][j]);
  for (int s=0;s<2;++s) for (int j=0;j<4;++j) hi[s*4+j] = (short)f2bf(kv[2+s][j]);
  const int slot = (kr&3)*16 + (kr>>2);            // key permutation
  char* kdst = kws + (size_t)blk*TILE_BYTES + slot*KROW + ds*32;
  *(bf16x8*)(kdst)    = lo;
  *(bf16x8*)(kdst+16) = hi;

  char* vdst = vws + (size_t)blk*TILE_BYTES + kr*2; // column kr (identity)
  for (int s=0;s<4;++s)
    for (int j=0;j<4;++j)
      *(unsigned short*)(vdst + (size_t)(ds*16 + s*4 + j)*KROW) = f2bf(vv[s][j]);
}

// Main: 8 waves, 2-way k-split (waves 0-3: k-tiles 0..31, waves 4-7: 32..63).
// Static softmax (exp2(s*mask), no max shift) => split combine is linear.
__global__ __launch_bounds__(512) void attn_main(const float* __restrict__ Q,
                                                 const float* __restrict__ Mk,
                                                 const char* __restrict__ kws,
                                                 const char* __restrict__ vws,
                                                 float* __restrict__ out) {
  __shared__ char Kbuf[2][2][TILE_BYTES];   // [half][buf]
  __shared__ char Vbuf[2][2][TILE_BYTES];
  __shared__ char Pbuf[8][16*KROW];         // per-wave P scratch

  // XCD-aware swizzle: blockIdx%8 ~ XCD; batch = xcd>>1 (2 XCDs per batch)
  const int idx = blockIdx.x;               // 0..255
  const int b   = (idx & 7) >> 1;           // 0..3
  const int qt  = ((idx >> 3) << 1) | (idx & 1);  // 0..63, bijective

  const int tid  = threadIdx.x;
  const int w    = tid >> 6;                // 0..7
  const int qw   = w & 3;                   // q-wave within half
  const int half = w >> 2;                  // k-split half
  const int lane = tid & 63;
  const int i16  = lane & 15;
  const int quad = lane >> 4;
  const int q0   = qt*TQ_ + qw*16;

  // Q A-frags with folded (1/sqrt(64))*log2(e): exp(s) = exp2(acc*mask)
  const float cs = 0.125f * 1.44269504088896f;
  bf16x8 aq[2];
  {
    const float* qp = Q + ((size_t)b*L_ + q0 + i16)*D_ + quad*8;
#pragma unroll
    for (int ks=0; ks<2; ++ks) {
      const f32x4* p = (const f32x4*)(qp + ks*32);
      f32x4 x0 = p[0], x1 = p[1];
      bf16x8 v;
      for (int j=0;j<4;++j) v[j]   = (short)f2bf(x0[j]*cs);
      for (int j=0;j<4;++j) v[4+j] = (short)f2bf(x1[j]*cs);
      aq[ks] = v;
    }
  }

  // ones B-frag for row-sum MFMA (bf16 1.0 = 0x3F80), no LDS read needed
  bf16x8 vone;
#pragma unroll
  for (int j=0;j<8;++j) vone[j] = (short)0x3F80;

  // mask base: row (q0+quad*4+r), col half*2048 + ktl*64 + 4*i16 (+t in f32x4)
  const float* mbase = Mk + ((size_t)b*L_ + q0 + quad*4)*(size_t)L_
                          + half*(NKH*TK_) + 4*i16;

  f32x4 O[4];
#pragma unroll
  for (int t=0;t<4;++t) O[t] = (f32x4){0.f,0.f,0.f,0.f};
  f32x4 l4 = (f32x4){0.f,0.f,0.f,0.f};      // row sums, MFMA-accumulated
  f32x4 cmv[4], nmv[4];
  bf16x8 sreg[5];                            // staged chunks (wave-uniform count)

  const size_t tb0 = (size_t)(b*NKT + half*NKH)*TILE_BYTES;

  // prologue: tile-0 chunks -> regs, mask tile-0 -> regs
  // wave qw owns 1KB chunks c = qw, qw+4, qw+8, qw+12, qw+16 (c<18);
  // c<9 -> K tile, c>=9 -> V tile. Static j index (no scratch spill).
#pragma unroll
  for (int j=0;j<5;++j) {
    const int c = qw + j*4;
    if (c < 18) {
      const char* gsrc = (c < 9)
          ? (kws + tb0 + (size_t)c*1024)
          : (vws + tb0 + (size_t)(c-9)*1024);
      sreg[j] = *(const bf16x8*)(gsrc + lane*16);
    }
  }
#pragma unroll
  for (int r=0;r<4;++r) cmv[r] = *(const f32x4*)(mbase + (size_t)r*L_);
#pragma unroll
  for (int r=0;r<4;++r) nmv[r] = cmv[r];

  for (int kt=0; kt<NKH; ++kt) {
    const int buf = kt & 1;

    // --- stage regs -> LDS (linear b128 chunk writes, conflict-free) ---
#pragma unroll
    for (int j=0;j<5;++j) {
      const int c = qw + j*4;
      if (c < 18) {
        char* ldst = (c < 9) ? &Kbuf[half][buf][c*1024]
                             : &Vbuf[half][buf][(c-9)*1024];
        *(bf16x8*)(ldst + lane*16) = sreg[j];
      }
    }
    __syncthreads();   // one barrier/tile: publishes buf, fences buf^1 reuse

    // --- issue next-tile global loads (overlap with compute below) ---
    if (kt+1 < NKH) {
      const size_t toff = tb0 + (size_t)(kt+1)*TILE_BYTES;
#pragma unroll
      for (int j=0;j<5;++j) {
        const int c = qw + j*4;
        if (c < 18) {
          const char* gsrc = (c < 9)
              ? (kws + toff + (size_t)c*1024)
              : (vws + toff + (size_t)(c-9)*1024);
          sreg[j] = *(const bf16x8*)(gsrc + lane*16);
        }
      }
      const size_t kc = (size_t)(kt+1)*TK_;
#pragma unroll
      for (int r=0;r<4;++r) nmv[r] = *(const f32x4*)(mbase + (size_t)r*L_ + kc);
    }

    // --- S = (Q*cs) K^T : 4 col-tiles x 2 k-steps ---
    f32x4 acc[4];
    const char* kb = Kbuf[half][buf];
#pragma unroll
    for (int t=0;t<4;++t) {
      acc[t] = (f32x4){0.f,0.f,0.f,0.f};
#pragma unroll
      for (int ks=0;ks<2;++ks) {
        bf16x8 bfr = *(const bf16x8*)(kb + (t*16+i16)*KROW + ks*64 + quad*16);
        acc[t] = __builtin_amdgcn_mfma_f32_16x16x32_bf16(aq[ks], bfr, acc[t], 0,0,0);
      }
    }

    // --- P = exp2(acc * mask). acc[t][r]: key 4*i16+t, row quad*4+r ---
    float p[16];
#pragma unroll
    for (int t=0;t<4;++t)
#pragma unroll
      for (int r=0;r<4;++r)
        p[t*4+r] = __builtin_amdgcn_exp2f(acc[t][r] * cmv[r][t]);

    // --- P -> own-wave LDS in A-layout; keys 4*i16+0..3 contiguous ---
    char* pb = Pbuf[w];
#pragma unroll
    for (int r=0;r<4;++r) {
      u16x4 pk;
      for (int t=0;t<4;++t) pk[t] = f2bf(p[t*4+r]);
      *(u16x4*)(pb + (quad*4+r)*KROW + i16*8) = pk;
    }

    // --- O += P V; row sums via ones-MFMA accumulated in C (no VALU) ---
    const char* vb = Vbuf[half][buf];
    bf16x8 af0 = *(const bf16x8*)(pb + i16*KROW +  0 + quad*16);
    bf16x8 af1 = *(const bf16x8*)(pb + i16*KROW + 64 + quad*16);
    l4 = __builtin_amdgcn_mfma_f32_16x16x32_bf16(af0, vone, l4, 0,0,0);
    l4 = __builtin_amdgcn_mfma_f32_16x16x32_bf16(af1, vone, l4, 0,0,0);
#pragma unroll
    for (int dt=0;dt<4;++dt) {
      bf16x8 vf0 = *(const bf16x8*)(vb + (dt*16+i16)*KROW +  0 + quad*16);
      O[dt] = __builtin_amdgcn_mfma_f32_16x16x32_bf16(af0, vf0, O[dt], 0,0,0);
      bf16x8 vf1 = *(const bf16x8*)(vb + (dt*16+i16)*KROW + 64 + quad*16);
      O[dt] = __builtin_amdgcn_mfma_f32_16x16x32_bf16(af1, vf1, O[dt], 0,0,0);
    }

#pragma unroll
    for (int r=0;r<4;++r) cmv[r] = nmv[r];
  }

  // ---- k-split combine: O = O0+O1, l = l0+l1 (exact: static softmax) ----
  // Overlay scratch on Kbuf/Pbuf. Need a barrier first: last tile's LDS
  // reads (this wave and others) must complete before overlay writes.
  float* Ol = (float*)&Kbuf[0][0][0];   // [4 qw][64 col][20] (16 rows + pad)
  float* Ll = (float*)&Pbuf[0][0];      // [4 qw][16 rows]
  __syncthreads();
  if (half == 1) {
#pragma unroll
    for (int t=0;t<4;++t)
      *(f32x4*)&Ol[((size_t)qw*64 + t*16 + i16)*20 + quad*4] = O[t];
    if (i16 == 0) {
#pragma unroll
      for (int r=0;r<4;++r) Ll[qw*16 + quad*4 + r] = l4[r];
    }
  }
  __syncthreads();
  if (half == 0) {
#pragma unroll
    for (int t=0;t<4;++t) {
      f32x4 op = *(const f32x4*)&Ol[((size_t)qw*64 + t*16 + i16)*20 + quad*4];
      O[t] += op;
    }
    float inv[4];
#pragma unroll
    for (int r=0;r<4;++r) inv[r] = 1.0f / (l4[r] + Ll[qw*16 + quad*4 + r]);
#pragma unroll
    for (int t=0;t<4;++t)
#pragma unroll
      for (int r=0;r<4;++r)
        out[((size_t)b*L_ + q0 + quad*4 + r)*D_ + t*16 + i16] = O[t][r]*inv[r];
  }
}

extern "C" void kernel_launch(void* const* d_in, const int* in_sizes, int n_in,
                              void* d_out, int out_size, void* d_ws, size_t ws_size,
                              hipStream_t stream) {
  const float* Q  = (const float*)d_in[0];
  const float* K  = (const float*)d_in[1];
  const float* V  = (const float*)d_in[2];
  const float* Mk = (const float*)d_in[3];
  // d_k (d_in[4]) is compile-time 64

  char* kws = (char*)d_ws;                                   // 2.36 MB
  char* vws = kws + (size_t)B_*NKT*TILE_BYTES;               // 2.36 MB (ws >= 4.72 MB)

  prep_kv  <<<B_*NKT, 256, 0, stream>>>(K, V, kws, vws);
  attn_main<<<B_*NQB, 512, 0, stream>>>(Q, Mk, kws, vws, (float*)d_out);
}